// Round 1
// baseline (92.728 us; speedup 1.0000x reference)
//
#include <hip/hip_runtime.h>
#include <stdint.h>

#define NROWS 16384
#define DIM 128

typedef __attribute__((ext_vector_type(8))) __bf16 bf16x8;
typedef __attribute__((ext_vector_type(4))) float f32x4;
typedef __attribute__((ext_vector_type(4))) unsigned int u32x4;

constexpr float TEMP_INV = 1.0f / 0.07f;
constexpr float LOG2E = 1.4426950408889634f;
constexpr float LN2 = 0.69314718055994531f;
constexpr float KAPPA = LOG2E * TEMP_INV;       // 20.609929...
// sqrt(KAPPA), baked into both normalized operands so MFMA output = exp2 arg
constexpr float SQRT_KAPPA = 4.53981600f;

__device__ __forceinline__ ushort f2bf(float x) {
  // round-to-nearest-even bf16 (inputs finite, no NaN path needed)
  uint32_t u = __builtin_bit_cast(uint32_t, x);
  uint32_t r = (u + 0x7fffu + ((u >> 16) & 1u)) >> 16;
  return (ushort)r;
}

// ---------------- Kernel 1: normalize, scale by sqrt(kappa), cast bf16 ----------------
// 16 rows/block, 16 threads/row, 8 elems/thread.
__global__ __launch_bounds__(256) void prep_kernel(
    const float* __restrict__ anchor, const float* __restrict__ positive,
    ushort* __restrict__ abar, ushort* __restrict__ pbar,
    float* __restrict__ pos_u)
{
  const int tid = threadIdx.x;
  const int row = blockIdx.x * 16 + (tid >> 4);
  const int c0 = (tid & 15) * 8;

  const float4* a4 = reinterpret_cast<const float4*>(anchor + (size_t)row * DIM + c0);
  const float4* p4 = reinterpret_cast<const float4*>(positive + (size_t)row * DIM + c0);
  float4 a0 = a4[0], a1 = a4[1];
  float4 p0 = p4[0], p1 = p4[1];

  float af[8] = {a0.x, a0.y, a0.z, a0.w, a1.x, a1.y, a1.z, a1.w};
  float pf[8] = {p0.x, p0.y, p0.z, p0.w, p1.x, p1.y, p1.z, p1.w};

  float sa = 0.f, sp = 0.f, dp = 0.f;
#pragma unroll
  for (int j = 0; j < 8; ++j) {
    sa += af[j] * af[j];
    sp += pf[j] * pf[j];
    dp += af[j] * pf[j];
  }
#pragma unroll
  for (int m = 1; m <= 8; m <<= 1) {
    sa += __shfl_xor(sa, m, 64);
    sp += __shfl_xor(sp, m, 64);
    dp += __shfl_xor(dp, m, 64);
  }
  float inva = 1.0f / fmaxf(sqrtf(sa), 1e-12f);
  float invp = 1.0f / fmaxf(sqrtf(sp), 1e-12f);
  float ca = inva * SQRT_KAPPA;
  float cp = invp * SQRT_KAPPA;

  ushort ua[8], up[8];
#pragma unroll
  for (int j = 0; j < 8; ++j) {
    ua[j] = f2bf(af[j] * ca);
    up[j] = f2bf(pf[j] * cp);
  }
  *reinterpret_cast<uint4*>(abar + (size_t)row * DIM + c0) = *reinterpret_cast<uint4*>(ua);
  *reinterpret_cast<uint4*>(pbar + (size_t)row * DIM + c0) = *reinterpret_cast<uint4*>(up);

  if ((tid & 15) == 0)
    pos_u[row] = dp * inva * invp * KAPPA;   // positive logit in log2 units
}

// ---------------- Kernel 2: fused GEMM + exp2 row-sum ----------------
// 256 blocks = (32 row-blocks of 512 rows) x (8 column splits of 2048 cols).
// 8 waves/block, each wave owns 64 rows (A fragments resident in 64 VGPRs).
// B tile (32 cols x 128 k, bf16) staged in XOR-swizzled LDS, double-buffered.
#define NSPLIT 8
#define BM 512
#define CPB (NROWS / NSPLIT)   // 2048 cols per block
#define BN 32
#define NIT (CPB / BN)         // 64 iterations

__global__ __launch_bounds__(512, 2) void lse_kernel(
    const ushort* __restrict__ abar,
    const ushort* __restrict__ pbar,
    float* __restrict__ sbuf /* [NSPLIT][NROWS] */)
{
  __shared__ alignas(16) char lds[2][BN * 256];   // 2 x 8 KiB

  const int tid = threadIdx.x;
  const int l = tid & 63;
  const int w = tid >> 6;
  const int r15 = l & 15;
  const int hi = l >> 4;

  const int bid = blockIdx.x;
  const int csplit = bid & 7;       // same split -> same XCD (round-robin) -> L2 reuse
  const int rowblk = bid >> 3;
  const int row0 = rowblk * BM + w * 64;
  const int col0 = csplit * CPB;

  const char* abase = (const char*)abar;
  const char* pbase = (const char*)pbar;

  // A fragments: a[rg][kk] covers rows row0+rg*16+r15, k = kk*32 + hi*8
  bf16x8 afrag[4][4];
#pragma unroll
  for (int rg = 0; rg < 4; ++rg)
#pragma unroll
    for (int kk = 0; kk < 4; ++kk) {
      size_t off = (size_t)(row0 + rg * 16 + r15) * 256 + (size_t)(kk * 32 + hi * 8) * 2;
      u32x4 v = *reinterpret_cast<const u32x4*>(abase + off);
      afrag[rg][kk] = __builtin_bit_cast(bf16x8, v);
    }

  float s[4][4];
#pragma unroll
  for (int rg = 0; rg < 4; ++rg)
#pragma unroll
    for (int rr = 0; rr < 4; ++rr) s[rg][rr] = 0.f;

  // staging: thread t handles tile byte t*16 (linear global read, swizzled LDS write)
  const int strow = tid >> 4;
  const int stlds = strow * 256 + (((tid & 15) * 16) ^ ((strow & 7) << 4));

  u32x4 stg = *reinterpret_cast<const u32x4*>(pbase + (size_t)col0 * 256 + tid * 16);
  *reinterpret_cast<u32x4*>(&lds[0][stlds]) = stg;
  __syncthreads();

  for (int it = 0; it < NIT; ++it) {
    const int cur = it & 1;
    if (it + 1 < NIT)
      stg = *reinterpret_cast<const u32x4*>(
          pbase + (size_t)(col0 + (it + 1) * BN) * 256 + tid * 16);

#pragma unroll
    for (int ct = 0; ct < 2; ++ct) {
      const int tr = ct * 16 + r15;
      const int sw = (tr & 7) << 4;
      const char* base = &lds[cur][tr * 256];
      bf16x8 bfrag[4];
#pragma unroll
      for (int kk = 0; kk < 4; ++kk) {
        const int cb = kk * 64 + hi * 16;
        u32x4 v = *reinterpret_cast<const u32x4*>(base + (cb ^ sw));
        bfrag[kk] = __builtin_bit_cast(bf16x8, v);
      }
#pragma unroll
      for (int rg = 0; rg < 4; ++rg) {
        f32x4 acc = {0.f, 0.f, 0.f, 0.f};
#pragma unroll
        for (int kk = 0; kk < 4; ++kk)
          acc = __builtin_amdgcn_mfma_f32_16x16x32_bf16(afrag[rg][kk], bfrag[kk], acc, 0, 0, 0);
        s[rg][0] += __builtin_amdgcn_exp2f(acc[0]);
        s[rg][1] += __builtin_amdgcn_exp2f(acc[1]);
        s[rg][2] += __builtin_amdgcn_exp2f(acc[2]);
        s[rg][3] += __builtin_amdgcn_exp2f(acc[3]);
      }
    }
    __syncthreads();
    if (it + 1 < NIT) {
      *reinterpret_cast<u32x4*>(&lds[cur ^ 1][stlds]) = stg;
      __syncthreads();
    }
  }

  // reduce partial sums across the 16 column-lanes; write deterministic split partials
#pragma unroll
  for (int rg = 0; rg < 4; ++rg)
#pragma unroll
    for (int rr = 0; rr < 4; ++rr) {
      float v = s[rg][rr];
      v += __shfl_xor(v, 1, 64);
      v += __shfl_xor(v, 2, 64);
      v += __shfl_xor(v, 4, 64);
      v += __shfl_xor(v, 8, 64);
      if (r15 == 0) {
        int grow = row0 + rg * 16 + hi * 4 + rr;   // C/D layout: row=(l>>4)*4+reg
        sbuf[(size_t)csplit * NROWS + grow] = v;
      }
    }
}

// ---------------- Kernel 3: finalize ----------------
__global__ __launch_bounds__(512) void finalize_kernel(
    const float* __restrict__ sbuf, const float* __restrict__ pos_u,
    float* __restrict__ out)
{
  const int tid = threadIdx.x;
  float acc = 0.f;
  for (int r = tid; r < NROWS; r += 512) {
    float s = 0.f;
#pragma unroll
    for (int c = 0; c < NSPLIT; ++c) s += sbuf[(size_t)c * NROWS + r];
    acc += LN2 * (__builtin_amdgcn_logf(s) - pos_u[r]);  // v_log_f32 = log2
  }
#pragma unroll
  for (int m = 1; m <= 32; m <<= 1) acc += __shfl_xor(acc, m, 64);
  __shared__ float red[8];
  if ((tid & 63) == 0) red[tid >> 6] = acc;
  __syncthreads();
  if (tid < 8) {
    float v = red[tid];
    v += __shfl_xor(v, 1, 64);
    v += __shfl_xor(v, 2, 64);
    v += __shfl_xor(v, 4, 64);
    if (tid == 0) out[0] = v * (1.0f / (float)NROWS);
  }
}

extern "C" void kernel_launch(void* const* d_in, const int* in_sizes, int n_in,
                              void* d_out, int out_size, void* d_ws, size_t ws_size,
                              hipStream_t stream) {
  const float* anchor = (const float*)d_in[0];
  const float* positive = (const float*)d_in[1];
  char* ws = (char*)d_ws;

  ushort* abar = (ushort*)ws;                                   // 4 MiB
  ushort* pbar = (ushort*)(ws + (size_t)NROWS * DIM * 2);       // 4 MiB
  float* pos_u = (float*)(ws + (size_t)NROWS * DIM * 4);        // 64 KiB
  float* sbuf = (float*)(ws + (size_t)NROWS * DIM * 4 + (size_t)NROWS * 4); // 512 KiB
  float* out = (float*)d_out;

  prep_kernel<<<NROWS / 16, 256, 0, stream>>>(anchor, positive, abar, pbar, pos_u);
  lse_kernel<<<NSPLIT * (NROWS / BM), 512, 0, stream>>>(abar, pbar, sbuf);
  finalize_kernel<<<1, 512, 0, stream>>>(sbuf, pos_u, out);
}

// Round 2
// 77.321 us; speedup vs baseline: 1.1993x; 1.1993x over previous
//
#include <hip/hip_runtime.h>
#include <stdint.h>

#define NROWS 16384
#define DIM 128

typedef __attribute__((ext_vector_type(8))) __bf16 bf16x8;
typedef __attribute__((ext_vector_type(4))) float f32x4;
typedef __attribute__((ext_vector_type(4))) unsigned int u32x4;

constexpr float TEMP_INV = 1.0f / 0.07f;
constexpr float LOG2E = 1.4426950408889634f;
constexpr float LN2 = 0.69314718055994531f;
constexpr float KAPPA = LOG2E * TEMP_INV;       // exp2-domain logit scale
constexpr float SQRT_KAPPA = 4.53981600f;       // baked into both operands

__device__ __forceinline__ ushort f2bf(float x) {
  uint32_t u = __builtin_bit_cast(uint32_t, x);
  uint32_t r = (u + 0x7fffu + ((u >> 16) & 1u)) >> 16;
  return (ushort)r;
}

// async global->LDS, 16B per lane; LDS dest is wave-uniform base + lane*16
__device__ __forceinline__ void gload_lds16(const void* g, void* l) {
  __builtin_amdgcn_global_load_lds(
      (const __attribute__((address_space(1))) unsigned int*)g,
      (__attribute__((address_space(3))) unsigned int*)l, 16, 0, 0);
}

// ---------------- Kernel 1: normalize, scale by sqrt(kappa), cast bf16 ----------------
__global__ __launch_bounds__(256) void prep_kernel(
    const float* __restrict__ anchor, const float* __restrict__ positive,
    ushort* __restrict__ abar, ushort* __restrict__ pbar,
    float* __restrict__ pos_u)
{
  const int tid = threadIdx.x;
  const int row = blockIdx.x * 16 + (tid >> 4);
  const int c0 = (tid & 15) * 8;

  const float4* a4 = reinterpret_cast<const float4*>(anchor + (size_t)row * DIM + c0);
  const float4* p4 = reinterpret_cast<const float4*>(positive + (size_t)row * DIM + c0);
  float4 a0 = a4[0], a1 = a4[1];
  float4 p0 = p4[0], p1 = p4[1];

  float af[8] = {a0.x, a0.y, a0.z, a0.w, a1.x, a1.y, a1.z, a1.w};
  float pf[8] = {p0.x, p0.y, p0.z, p0.w, p1.x, p1.y, p1.z, p1.w};

  float sa = 0.f, sp = 0.f, dp = 0.f;
#pragma unroll
  for (int j = 0; j < 8; ++j) {
    sa += af[j] * af[j];
    sp += pf[j] * pf[j];
    dp += af[j] * pf[j];
  }
#pragma unroll
  for (int m = 1; m <= 8; m <<= 1) {
    sa += __shfl_xor(sa, m, 64);
    sp += __shfl_xor(sp, m, 64);
    dp += __shfl_xor(dp, m, 64);
  }
  float inva = 1.0f / fmaxf(sqrtf(sa), 1e-12f);
  float invp = 1.0f / fmaxf(sqrtf(sp), 1e-12f);
  float ca = inva * SQRT_KAPPA;
  float cp = invp * SQRT_KAPPA;

  ushort ua[8], up[8];
#pragma unroll
  for (int j = 0; j < 8; ++j) {
    ua[j] = f2bf(af[j] * ca);
    up[j] = f2bf(pf[j] * cp);
  }
  *reinterpret_cast<uint4*>(abar + (size_t)row * DIM + c0) = *reinterpret_cast<uint4*>(ua);
  *reinterpret_cast<uint4*>(pbar + (size_t)row * DIM + c0) = *reinterpret_cast<uint4*>(up);

  if ((tid & 15) == 0)
    pos_u[row] = dp * inva * invp * KAPPA;
}

// ---------------- Kernel 2: fused GEMM + exp2 row-sum ----------------
// 512 blocks = (64 row-blocks of 256) x (8 col splits of 2048) -> 2 blocks/CU.
// 8 waves/block, each wave owns 32 rows. B tile (32 cols x 128 k) streamed
// via global_load_lds into a 4-deep ring buffer; 1 barrier/iter, counted vmcnt.
#define NSPLIT 8
#define BM 256
#define CPB (NROWS / NSPLIT)   // 2048
#define BN 32
#define NIT (CPB / BN)         // 64
#define NBUF 4

__global__ __launch_bounds__(512, 4) void lse_kernel(
    const ushort* __restrict__ abar,
    const ushort* __restrict__ pbar,
    float* __restrict__ sbuf /* [NSPLIT][NROWS] */)
{
  __shared__ alignas(16) char lds[NBUF][BN * 256];   // 4 x 8 KiB

  const int tid = threadIdx.x;
  const int l = tid & 63;
  const int w = tid >> 6;
  const int r15 = l & 15;
  const int hi = l >> 4;

  const int bid = blockIdx.x;
  const int csplit = bid & 7;       // split == XCD (round-robin) -> pbar slice L2-resident
  const int rowblk = bid >> 3;
  const int row0 = rowblk * BM + w * 32;
  const int col0 = csplit * CPB;

  const char* abase = (const char*)abar;
  const char* pbase = (const char*)pbar;

  // A fragments: rows row0 + rg*16 + r15, k = kk*32 + hi*8
  bf16x8 afrag[2][4];
#pragma unroll
  for (int rg = 0; rg < 2; ++rg)
#pragma unroll
    for (int kk = 0; kk < 4; ++kk) {
      size_t off = (size_t)(row0 + rg * 16 + r15) * 256 + (size_t)(kk * 32 + hi * 8) * 2;
      u32x4 v = *reinterpret_cast<const u32x4*>(abase + off);
      afrag[rg][kk] = __builtin_bit_cast(bf16x8, v);
    }

  float s[2][4];
#pragma unroll
  for (int rg = 0; rg < 2; ++rg)
#pragma unroll
    for (int rr = 0; rr < 4; ++rr) s[rg][rr] = 0.f;

  // Staging: wave w fills LDS rows [4w,4w+4) linearly; swizzle applied on the
  // GLOBAL source (involution), so LDS[r][c] = tile[r][c ^ (r&7)] as before.
  const int trow = w * 4 + (l >> 4);
  const size_t src0 = (size_t)(col0 + trow) * 256 + (size_t)(((l & 15) ^ (trow & 7)) * 16);
  void* ldst[NBUF];
#pragma unroll
  for (int b = 0; b < NBUF; ++b) ldst[b] = &lds[b][w * 1024];

  // prologue: 2 tiles in flight
  gload_lds16(pbase + src0, ldst[0]);
  __builtin_amdgcn_sched_barrier(0);
  gload_lds16(pbase + src0 + 8192, ldst[1]);
  __builtin_amdgcn_sched_barrier(0);

  for (int it = 0; it < NIT; ++it) {
    if (it < NIT - 1) {
      asm volatile("s_waitcnt vmcnt(1)" ::: "memory");   // stage(it) landed, stage(it+1) in flight
    } else {
      asm volatile("s_waitcnt vmcnt(0)" ::: "memory");
    }
    __builtin_amdgcn_s_barrier();
    asm volatile("" ::: "memory");
    __builtin_amdgcn_sched_barrier(0);

    if (it + 2 < NIT)
      gload_lds16(pbase + src0 + (size_t)(it + 2) * 8192, ldst[(it + 2) & 3]);

    const char* bufp = lds[it & 3];
#pragma unroll
    for (int ct = 0; ct < 2; ++ct) {
      const int tr = ct * 16 + r15;
      const int sw = (tr & 7) << 4;
      const char* base = bufp + tr * 256;
      bf16x8 bfrag[4];
#pragma unroll
      for (int kk = 0; kk < 4; ++kk) {
        const int cb = kk * 64 + hi * 16;
        u32x4 v = *reinterpret_cast<const u32x4*>(base + (cb ^ sw));
        bfrag[kk] = __builtin_bit_cast(bf16x8, v);
      }
      __builtin_amdgcn_s_setprio(1);
#pragma unroll
      for (int rg = 0; rg < 2; ++rg) {
        f32x4 acc = {0.f, 0.f, 0.f, 0.f};
#pragma unroll
        for (int kk = 0; kk < 4; ++kk)
          acc = __builtin_amdgcn_mfma_f32_16x16x32_bf16(afrag[rg][kk], bfrag[kk], acc, 0, 0, 0);
        s[rg][0] += __builtin_amdgcn_exp2f(acc[0]);
        s[rg][1] += __builtin_amdgcn_exp2f(acc[1]);
        s[rg][2] += __builtin_amdgcn_exp2f(acc[2]);
        s[rg][3] += __builtin_amdgcn_exp2f(acc[3]);
      }
      __builtin_amdgcn_s_setprio(0);
    }
  }

  // reduce partials across the 16 column-lanes; deterministic split partials
#pragma unroll
  for (int rg = 0; rg < 2; ++rg)
#pragma unroll
    for (int rr = 0; rr < 4; ++rr) {
      float v = s[rg][rr];
      v += __shfl_xor(v, 1, 64);
      v += __shfl_xor(v, 2, 64);
      v += __shfl_xor(v, 4, 64);
      v += __shfl_xor(v, 8, 64);
      if (r15 == 0) {
        int grow = row0 + rg * 16 + hi * 4 + rr;   // C/D: row=(l>>4)*4+reg
        sbuf[(size_t)csplit * NROWS + grow] = v;
      }
    }
}

// ---------------- Kernel 3a/3b: finalize ----------------
__global__ __launch_bounds__(256) void finalize1(
    const float* __restrict__ sbuf, const float* __restrict__ pos_u,
    float* __restrict__ partial)
{
  const int tid = threadIdx.x;
  const int r = blockIdx.x * 256 + tid;
  float ssum = 0.f;
#pragma unroll
  for (int c = 0; c < NSPLIT; ++c) ssum += sbuf[(size_t)c * NROWS + r];
  float acc = LN2 * (__builtin_amdgcn_logf(ssum) - pos_u[r]);
#pragma unroll
  for (int m = 1; m <= 32; m <<= 1) acc += __shfl_xor(acc, m, 64);
  __shared__ float red[4];
  if ((tid & 63) == 0) red[tid >> 6] = acc;
  __syncthreads();
  if (tid == 0) partial[blockIdx.x] = red[0] + red[1] + red[2] + red[3];
}

__global__ __launch_bounds__(64) void finalize2(
    const float* __restrict__ partial, float* __restrict__ out)
{
  float v = partial[threadIdx.x];
#pragma unroll
  for (int m = 1; m <= 32; m <<= 1) v += __shfl_xor(v, m, 64);
  if (threadIdx.x == 0) out[0] = v * (1.0f / (float)NROWS);
}

extern "C" void kernel_launch(void* const* d_in, const int* in_sizes, int n_in,
                              void* d_out, int out_size, void* d_ws, size_t ws_size,
                              hipStream_t stream) {
  const float* anchor = (const float*)d_in[0];
  const float* positive = (const float*)d_in[1];
  char* ws = (char*)d_ws;

  ushort* abar = (ushort*)ws;                                         // 4 MiB
  ushort* pbar = (ushort*)(ws + (size_t)NROWS * DIM * 2);             // 4 MiB
  float* pos_u = (float*)(ws + (size_t)NROWS * DIM * 4);              // 64 KiB
  float* sbuf = (float*)(ws + (size_t)NROWS * DIM * 4 + (size_t)NROWS * 4);           // 512 KiB
  float* partial = (float*)(ws + (size_t)NROWS * DIM * 4 + (size_t)NROWS * 4
                            + (size_t)NSPLIT * NROWS * 4);            // 256 B
  float* out = (float*)d_out;

  prep_kernel<<<NROWS / 16, 256, 0, stream>>>(anchor, positive, abar, pbar, pos_u);
  lse_kernel<<<NSPLIT * (NROWS / BM), 512, 0, stream>>>(abar, pbar, sbuf);
  finalize1<<<NROWS / 256, 256, 0, stream>>>(sbuf, pos_u, partial);
  finalize2<<<1, 64, 0, stream>>>(partial, out);
}